// Round 7
// baseline (375.486 us; speedup 1.0000x reference)
//
#include <hip/hip_runtime.h>
#include <hip/hip_bf16.h>

#define N_NODES 100000
#define N_EDGES 3200000
#define F_IN 256
#define D_OUT 64
#define BATCH 4096
#define N_FIELDS 20
#define N_ENTRIES (BATCH * N_FIELDS)          // 81920

#define NBUCKET 512
#define NPB 196                                // nodes per bucket
#define N_PAD (NBUCKET * NPB)                  // 100352
#define EPB 8192                               // edges per histogram/scatter block
#define NBLK ((N_EDGES + EPB - 1) / EPB)       // 391
#define BUCKET_CAP 8192
#define SCAN_B 512
#define NSB (N_PAD / SCAN_B)                   // 196

typedef short bf16x8 __attribute__((ext_vector_type(8)));
typedef float f32x4 __attribute__((ext_vector_type(4)));

static __device__ __forceinline__ float bfbits2f(unsigned short u) {
    return __uint_as_float((unsigned)u << 16);
}
static __device__ __forceinline__ unsigned short f2bf_bits(float x) {
    __hip_bfloat16 h = __float2bfloat16(x);
    return *reinterpret_cast<unsigned short*>(&h);
}

// ---- 1. per-block bucket histogram ----
__global__ __launch_bounds__(256) void k_hist(const int* __restrict__ dst,
                                              unsigned short* __restrict__ perBlockCnt) {
    __shared__ unsigned hist[NBUCKET];
    hist[threadIdx.x] = 0;
    hist[threadIdx.x + 256] = 0;
    __syncthreads();
    int base = blockIdx.x * EPB;
#pragma unroll 4
    for (int k = 0; k < EPB / 256; k++) {
        int e = base + k * 256 + threadIdx.x;
        if (e < N_EDGES) atomicAdd(&hist[(unsigned)dst[e] / NPB], 1u);
    }
    __syncthreads();
    perBlockCnt[(threadIdx.x) * NBLK + blockIdx.x] = (unsigned short)hist[threadIdx.x];
    perBlockCnt[(threadIdx.x + 256) * NBLK + blockIdx.x] = (unsigned short)hist[threadIdx.x + 256];
}

// ---- 2a. per-bucket wave scan across blocks ----
__global__ __launch_bounds__(256) void k_colscan_w(unsigned short* __restrict__ perBlockCnt,
                                                   int* __restrict__ bucketTot) {
    int gw = (blockIdx.x * 256 + threadIdx.x) >> 6;
    int lane = threadIdx.x & 63;
    if (gw >= NBUCKET) return;
    unsigned running = 0;
    for (int c = 0; c < (NBLK + 63) / 64; c++) {
        int blk = c * 64 + lane;
        int idx = gw * NBLK + blk;
        unsigned v = (blk < NBLK) ? perBlockCnt[idx] : 0;
        unsigned orig = v;
#pragma unroll
        for (int d = 1; d < 64; d <<= 1) {
            unsigned t = __shfl_up(v, d, 64);
            if (lane >= d) v += t;
        }
        if (blk < NBLK) perBlockCnt[idx] = (unsigned short)(running + v - orig);
        running += __shfl(v, 63, 64);
    }
    if (lane == 0) bucketTot[gw] = (int)running;
}

// ---- 2b. scan 512 bucket totals -> bucketBase[513] ----
__global__ __launch_bounds__(512) void k_basescan(const int* __restrict__ bucketTot,
                                                  int* __restrict__ bucketBase) {
    __shared__ int sh[NBUCKET];
    int tid = threadIdx.x;
    int v = bucketTot[tid];
    sh[tid] = v;
    __syncthreads();
    for (int off = 1; off < NBUCKET; off <<= 1) {
        int t = (tid >= off) ? sh[tid - off] : 0;
        __syncthreads();
        sh[tid] += t;
        __syncthreads();
    }
    bucketBase[tid] = sh[tid] - v;
    if (tid == NBUCKET - 1) bucketBase[NBUCKET] = sh[NBUCKET - 1];
}

// ---- 3. scatter edges into bucket-grouped order ----
__global__ __launch_bounds__(256) void k_bucket_scatter(const int* __restrict__ src,
                                                        const int* __restrict__ dst,
                                                        const int* __restrict__ bucketBase,
                                                        const unsigned short* __restrict__ perBlockCnt,
                                                        unsigned* __restrict__ bucketData) {
    __shared__ unsigned slotBase[NBUCKET];
    slotBase[threadIdx.x] = (unsigned)bucketBase[threadIdx.x] +
                            (unsigned)perBlockCnt[threadIdx.x * NBLK + blockIdx.x];
    slotBase[threadIdx.x + 256] = (unsigned)bucketBase[threadIdx.x + 256] +
                                  (unsigned)perBlockCnt[(threadIdx.x + 256) * NBLK + blockIdx.x];
    __syncthreads();
    int base = blockIdx.x * EPB;
#pragma unroll 4
    for (int k = 0; k < EPB / 256; k++) {
        int e = base + k * 256 + threadIdx.x;
        if (e < N_EDGES) {
            unsigned s = (unsigned)src[e];
            unsigned d = (unsigned)dst[e];
            unsigned b = d / NPB;
            unsigned ld = d - b * NPB;
            unsigned slot = atomicAdd(&slotBase[b], 1u);
            bucketData[slot] = s | (ld << 17);
        }
    }
}

// ---- 4. per-bucket CSR build + in-place permute ----
__global__ __launch_bounds__(256) void k_bucket_csr(unsigned* __restrict__ bucketData,
                                                    const int* __restrict__ bucketBase,
                                                    int* __restrict__ rowStart,
                                                    float* __restrict__ dis) {
    __shared__ unsigned words[BUCKET_CAP];
    __shared__ unsigned srcsorted[BUCKET_CAP];
    __shared__ unsigned nodeCount[NPB];
    __shared__ unsigned sscan[256];
    __shared__ unsigned cursor[NPB];

    int b = blockIdx.x;
    int base = bucketBase[b];
    int cnt = bucketBase[b + 1] - base;
    if (cnt > BUCKET_CAP) cnt = BUCKET_CAP;
    int tid = threadIdx.x;

    for (int j = tid; j < NPB; j += 256) nodeCount[j] = 0;
    __syncthreads();

    for (int i = tid; i < cnt; i += 256) {
        unsigned w = bucketData[base + i];
        words[i] = w;
        atomicAdd(&nodeCount[w >> 17], 1u);
    }
    __syncthreads();

    unsigned v = (tid < NPB) ? nodeCount[tid] : 0;
    sscan[tid] = v;
    __syncthreads();
    for (int off = 1; off < 256; off <<= 1) {
        unsigned t = (tid >= off) ? sscan[tid - off] : 0;
        __syncthreads();
        sscan[tid] += t;
        __syncthreads();
    }

    int firstNode = b * NPB;
    if (tid < NPB) {
        unsigned excl = sscan[tid] - v;
        rowStart[firstNode + tid] = base + (int)excl;
        dis[firstNode + tid] = rsqrtf((float)(v + 1));
        cursor[tid] = excl;
    }
    __syncthreads();

    for (int i = tid; i < cnt; i += 256) {
        unsigned w = words[i];
        unsigned slot = atomicAdd(&cursor[w >> 17], 1u);
        srcsorted[slot] = w & 0x1FFFFu;
    }
    __syncthreads();

    for (int i = tid; i < cnt; i += 256)
        bucketData[base + i] = srcsorted[i];
}

// ---- 5. W (f32, K x N) -> bf16 W^T (N x K) ----
__global__ void k_wtconv(const float* __restrict__ W, unsigned short* __restrict__ WTbf) {
    int i = blockIdx.x * blockDim.x + threadIdx.x;
    if (i >= D_OUT * F_IN) return;
    int n = i >> 8, k = i & 255;
    WTbf[i] = f2bf_bits(W[k * D_OUT + n]);
}

// ---- 6. MFMA GEMM: y[row] = dis[row] * (X[row] @ W), bf16 out ----
__global__ __launch_bounds__(256) void k_gemm_mfma(const float* __restrict__ feat,
                                                   const unsigned short* __restrict__ WTbf,
                                                   const float* __restrict__ dis,
                                                   unsigned short* __restrict__ y) {
    __shared__ unsigned short wt[64 * 264];
    int tid = threadIdx.x;
    {
        int r = tid >> 2, seg = tid & 3;
        const uint4* gsrc = (const uint4*)(WTbf + r * 256 + seg * 64);
        uint4* ldst = (uint4*)&wt[r * 264 + seg * 64];
#pragma unroll
        for (int q = 0; q < 8; q++) ldst[q] = gsrc[q];
    }
    __syncthreads();

    int wave = tid >> 6, lane = tid & 63;
    int quad = lane >> 4, m = lane & 15;
    int rowT = blockIdx.x * 64 + wave * 16;
    int row = rowT + m;
    int rowC = (row < N_NODES) ? row : (N_NODES - 1);
    const float* fb = feat + (size_t)rowC * F_IN + quad * 8;

    f32x4 acc0 = {0.f, 0.f, 0.f, 0.f};
    f32x4 acc1 = acc0, acc2 = acc0, acc3 = acc0;

#pragma unroll
    for (int kk = 0; kk < 8; kk++) {
        float4 x0 = *(const float4*)(fb + kk * 32);
        float4 x1 = *(const float4*)(fb + kk * 32 + 4);
        bf16x8 a;
        a[0] = (short)f2bf_bits(x0.x); a[1] = (short)f2bf_bits(x0.y);
        a[2] = (short)f2bf_bits(x0.z); a[3] = (short)f2bf_bits(x0.w);
        a[4] = (short)f2bf_bits(x1.x); a[5] = (short)f2bf_bits(x1.y);
        a[6] = (short)f2bf_bits(x1.z); a[7] = (short)f2bf_bits(x1.w);
        int kbase = kk * 32 + quad * 8;
        bf16x8 b0 = *(const bf16x8*)&wt[(0 * 16 + m) * 264 + kbase];
        bf16x8 b1 = *(const bf16x8*)&wt[(1 * 16 + m) * 264 + kbase];
        bf16x8 b2 = *(const bf16x8*)&wt[(2 * 16 + m) * 264 + kbase];
        bf16x8 b3 = *(const bf16x8*)&wt[(3 * 16 + m) * 264 + kbase];
        acc0 = __builtin_amdgcn_mfma_f32_16x16x32_bf16(a, b0, acc0, 0, 0, 0);
        acc1 = __builtin_amdgcn_mfma_f32_16x16x32_bf16(a, b1, acc1, 0, 0, 0);
        acc2 = __builtin_amdgcn_mfma_f32_16x16x32_bf16(a, b2, acc2, 0, 0, 0);
        acc3 = __builtin_amdgcn_mfma_f32_16x16x32_bf16(a, b3, acc3, 0, 0, 0);
    }

    float dv[4];
#pragma unroll
    for (int r = 0; r < 4; r++) {
        int rr = rowT + quad * 4 + r;
        dv[r] = dis[(rr < N_NODES) ? rr : 0];
    }
#pragma unroll
    for (int r = 0; r < 4; r++) {
        int rr = rowT + quad * 4 + r;
        if (rr < N_NODES) {
            size_t o = (size_t)rr * D_OUT + m;
            y[o]      = f2bf_bits(acc0[r] * dv[r]);
            y[o + 16] = f2bf_bits(acc1[r] * dv[r]);
            y[o + 32] = f2bf_bits(acc2[r] * dv[r]);
            y[o + 48] = f2bf_bits(acc3[r] * dv[r]);
        }
    }
}

// ---- 7a. entry count per node ----
__global__ __launch_bounds__(256) void kx_cnt(const int* __restrict__ x,
                                              int* __restrict__ nodeEntCnt) {
    int ent = blockIdx.x * blockDim.x + threadIdx.x;
    if (ent < N_ENTRIES) atomicAdd(&nodeEntCnt[x[ent]], 1);
}

// ---- 7b. per-block exclusive scan of nodeEntCnt ----
__global__ __launch_bounds__(512) void kx_scan_local(const int* __restrict__ nodeEntCnt,
                                                     int* __restrict__ localE,
                                                     int* __restrict__ blockSumsE) {
    __shared__ int sh[SCAN_B];
    int g = blockIdx.x * SCAN_B + threadIdx.x;
    int v = (g < N_PAD) ? nodeEntCnt[g] : 0;
    sh[threadIdx.x] = v;
    __syncthreads();
    for (int off = 1; off < SCAN_B; off <<= 1) {
        int t = (threadIdx.x >= off) ? sh[threadIdx.x - off] : 0;
        __syncthreads();
        sh[threadIdx.x] += t;
        __syncthreads();
    }
    int incl = sh[threadIdx.x];
    if (g < N_PAD) localE[g] = incl - v;
    if (threadIdx.x == SCAN_B - 1) blockSumsE[blockIdx.x] = incl;
}

// ---- 7c. serial scan of 196 block sums ----
__global__ void kx_scan_blocks(const int* __restrict__ blockSumsE,
                               int* __restrict__ blockBaseE) {
    if (threadIdx.x == 0 && blockIdx.x == 0) {
        int s = 0;
        for (int i = 0; i < NSB; i++) {
            blockBaseE[i] = s;
            s += blockSumsE[i];
        }
    }
}

// ---- 7d. scatter entry ids grouped by node (localE becomes local END) ----
__global__ __launch_bounds__(256) void kx_scatter(const int* __restrict__ x,
                                                  int* __restrict__ localE,
                                                  const int* __restrict__ blockBaseE,
                                                  int* __restrict__ entGrouped) {
    int ent = blockIdx.x * blockDim.x + threadIdx.x;
    if (ent < N_ENTRIES) {
        int node = x[ent];
        int posL = atomicAdd(&localE[node], 1);
        entGrouped[blockBaseE[node >> 9] + posL] = ent;
    }
}

// ---- 8. dedup aggregation: one wave per node; gather once, write all dups ----
__global__ __launch_bounds__(256) void k_agg(const int* __restrict__ entGrouped,
                                             const int* __restrict__ localE,
                                             const int* __restrict__ blockBaseE,
                                             const int* __restrict__ rowStart,
                                             const unsigned* __restrict__ sortedSrc,
                                             const unsigned short* __restrict__ y,
                                             const float* __restrict__ b,
                                             float* __restrict__ out) {
    int g = blockIdx.x * blockDim.x + threadIdx.x;
    int i = g >> 6, lane = g & 63;
    if (i >= N_PAD) return;
    // entry range from post-scatter localE (holds local END) + block bases
    int gEnd = blockBaseE[i >> 9] + localE[i];
    int gStart = (i == 0) ? 0 : (blockBaseE[(i - 1) >> 9] + localE[i - 1]);
    int cntEnt = gEnd - gStart;
    if (cntEnt <= 0) return;

    int start = rowStart[i];
    int cnt = rowStart[i + 1] - start;
    float disI = rsqrtf((float)(cnt + 1));
    float self = bfbits2f(y[(size_t)i * D_OUT + lane]);
    float s0 = 0.f, s1 = 0.f, s2 = 0.f, s3 = 0.f;
    int e = 0;
    for (; e + 4 <= cnt; e += 4) {
        unsigned i0 = sortedSrc[start + e];
        unsigned i1 = sortedSrc[start + e + 1];
        unsigned i2 = sortedSrc[start + e + 2];
        unsigned i3 = sortedSrc[start + e + 3];
        s0 += bfbits2f(y[(size_t)i0 * D_OUT + lane]);
        s1 += bfbits2f(y[(size_t)i1 * D_OUT + lane]);
        s2 += bfbits2f(y[(size_t)i2 * D_OUT + lane]);
        s3 += bfbits2f(y[(size_t)i3 * D_OUT + lane]);
    }
    for (; e < cnt; e++) {
        unsigned i0 = sortedSrc[start + e];
        s0 += bfbits2f(y[(size_t)i0 * D_OUT + lane]);
    }
    float val = disI * (self + ((s0 + s1) + (s2 + s3))) + b[lane];
    for (int j = 0; j < cntEnt; j++) {
        int ent = entGrouped[gStart + j];
        out[(size_t)ent * D_OUT + lane] = val;
    }
}

extern "C" void kernel_launch(void* const* d_in, const int* in_sizes, int n_in,
                              void* d_out, int out_size, void* d_ws, size_t ws_size,
                              hipStream_t stream) {
    const float* feat     = (const float*)d_in[0];
    const int* edge_index = (const int*)d_in[1];
    const float* W        = (const float*)d_in[2];
    const float* bsrc     = (const float*)d_in[3];
    const int* x          = (const int*)d_in[4];
    float* out            = (float*)d_out;

    const int* src = edge_index;
    const int* dst = edge_index + N_EDGES;

    // workspace layout (256B aligned) — ~27.25 MB total.
    // Region [0 .. ~404 KB) is double-used: bucket-sort metadata first, then
    // (after k_bucket_csr) aliased by nodeEntCnt, then by entGrouped
    // (each alias's first use is stream-ordered after the prior user's last).
    char* ws = (char*)d_ws;
    size_t off = 0;
    auto alloc = [&](size_t bytes) {
        size_t o = off;
        off = (off + bytes + 255) & ~(size_t)255;
        return o;
    };
    int* bucketBase = (int*)(ws + alloc((size_t)(NBUCKET + 1) * 4));          // 0
    int* bucketTot  = (int*)(ws + alloc((size_t)NBUCKET * 4));
    unsigned short* perBlockCnt = (unsigned short*)(ws + alloc((size_t)NBUCKET * NBLK * 2));
    // aliases of the dead bucket-metadata region:
    int* nodeEntCnt = (int*)(ws + 0);          // needs 401,408 B <= 404,736 B region
    int* entGrouped = (int*)(ws + 0);          // needs 327,680 B, after nodeEntCnt dies
    int*   rowStart = (int*)(ws + alloc((size_t)(N_PAD + 256) * 4));
    float* dis      = (float*)(ws + alloc((size_t)(N_PAD + 256) * 4));
    unsigned short* WTbf = (unsigned short*)(ws + alloc((size_t)D_OUT * F_IN * 2));
    int* localE     = (int*)(ws + alloc((size_t)N_PAD * 4));
    int* blockSumsE = (int*)(ws + alloc((size_t)NSB * 4));
    int* blockBaseE = (int*)(ws + alloc((size_t)NSB * 4));
    unsigned* bucketData = (unsigned*)(ws + alloc((size_t)N_EDGES * 4));
    unsigned short* y = (unsigned short*)(ws + alloc((size_t)N_NODES * D_OUT * 2));
    (void)ws_size; (void)in_sizes; (void)n_in; (void)out_size;

    const int T = 256;
    k_hist<<<NBLK, T, 0, stream>>>(dst, perBlockCnt);
    k_colscan_w<<<(NBUCKET * 64 + T - 1) / T, T, 0, stream>>>(perBlockCnt, bucketTot);
    k_basescan<<<1, NBUCKET, 0, stream>>>(bucketTot, bucketBase);
    k_bucket_scatter<<<NBLK, T, 0, stream>>>(src, dst, bucketBase, perBlockCnt, bucketData);
    k_bucket_csr<<<NBUCKET, T, 0, stream>>>(bucketData, bucketBase, rowStart, dis);
    k_wtconv<<<(D_OUT * F_IN + T - 1) / T, T, 0, stream>>>(W, WTbf);
    k_gemm_mfma<<<(N_NODES + 63) / 64, T, 0, stream>>>(feat, WTbf, dis, y);
    // entry grouping (aliased region now free)
    hipMemsetAsync(nodeEntCnt, 0, (size_t)N_PAD * 4, stream);
    kx_cnt<<<(N_ENTRIES + T - 1) / T, T, 0, stream>>>(x, nodeEntCnt);
    kx_scan_local<<<NSB, SCAN_B, 0, stream>>>(nodeEntCnt, localE, blockSumsE);
    kx_scan_blocks<<<1, 64, 0, stream>>>(blockSumsE, blockBaseE);
    kx_scatter<<<(N_ENTRIES + T - 1) / T, T, 0, stream>>>(x, localE, blockBaseE, entGrouped);
    k_agg<<<((size_t)N_PAD * 64 + T - 1) / T, T, 0, stream>>>(
        entGrouped, localE, blockBaseE, rowStart, bucketData, y, bsrc, out);
}

// Round 8
// 341.604 us; speedup vs baseline: 1.0992x; 1.0992x over previous
//
#include <hip/hip_runtime.h>
#include <hip/hip_bf16.h>

#define N_NODES 100000
#define N_EDGES 3200000
#define F_IN 256
#define D_OUT 64
#define BATCH 4096
#define N_FIELDS 20
#define N_ENTRIES (BATCH * N_FIELDS)          // 81920

#define NBUCKET 512
#define NPB 196                                // nodes per bucket
#define N_PAD (NBUCKET * NPB)                  // 100352
#define EPB 8192                               // edges per histogram/scatter block
#define NBLK ((N_EDGES + EPB - 1) / EPB)       // 391
#define BUCKET_CAP 8192
#define SCAN_B 512
#define NSB (N_PAD / SCAN_B)                   // 196

typedef short bf16x8 __attribute__((ext_vector_type(8)));
typedef float f32x4 __attribute__((ext_vector_type(4)));

static __device__ __forceinline__ float bfbits2f(unsigned short u) {
    return __uint_as_float((unsigned)u << 16);
}
static __device__ __forceinline__ unsigned short f2bf_bits(float x) {
    __hip_bfloat16 h = __float2bfloat16(x);
    return *reinterpret_cast<unsigned short*>(&h);
}

// ---- 1. per-block bucket histogram (uint4-vectorized dst reads) ----
__global__ __launch_bounds__(256) void k_hist(const uint4* __restrict__ dst4,
                                              unsigned short* __restrict__ perBlockCnt) {
    __shared__ unsigned hist[NBUCKET];
    hist[threadIdx.x] = 0;
    hist[threadIdx.x + 256] = 0;
    __syncthreads();
    int base4 = blockIdx.x * (EPB / 4);
#pragma unroll
    for (int k = 0; k < EPB / 1024; k++) {
        int e4 = base4 + k * 256 + threadIdx.x;
        if (e4 < N_EDGES / 4) {
            uint4 d = dst4[e4];
            atomicAdd(&hist[d.x / NPB], 1u);
            atomicAdd(&hist[d.y / NPB], 1u);
            atomicAdd(&hist[d.z / NPB], 1u);
            atomicAdd(&hist[d.w / NPB], 1u);
        }
    }
    __syncthreads();
    perBlockCnt[(threadIdx.x) * NBLK + blockIdx.x] = (unsigned short)hist[threadIdx.x];
    perBlockCnt[(threadIdx.x + 256) * NBLK + blockIdx.x] = (unsigned short)hist[threadIdx.x + 256];
}

// ---- 2a. per-bucket wave scan across blocks ----
__global__ __launch_bounds__(256) void k_colscan_w(unsigned short* __restrict__ perBlockCnt,
                                                   int* __restrict__ bucketTot) {
    int gw = (blockIdx.x * 256 + threadIdx.x) >> 6;
    int lane = threadIdx.x & 63;
    if (gw >= NBUCKET) return;
    unsigned running = 0;
    for (int c = 0; c < (NBLK + 63) / 64; c++) {
        int blk = c * 64 + lane;
        int idx = gw * NBLK + blk;
        unsigned v = (blk < NBLK) ? perBlockCnt[idx] : 0;
        unsigned orig = v;
#pragma unroll
        for (int d = 1; d < 64; d <<= 1) {
            unsigned t = __shfl_up(v, d, 64);
            if (lane >= d) v += t;
        }
        if (blk < NBLK) perBlockCnt[idx] = (unsigned short)(running + v - orig);
        running += __shfl(v, 63, 64);
    }
    if (lane == 0) bucketTot[gw] = (int)running;
}

// ---- 2b. scan 512 bucket totals -> bucketBase[513] ----
__global__ __launch_bounds__(512) void k_basescan(const int* __restrict__ bucketTot,
                                                  int* __restrict__ bucketBase) {
    __shared__ int sh[NBUCKET];
    int tid = threadIdx.x;
    int v = bucketTot[tid];
    sh[tid] = v;
    __syncthreads();
    for (int off = 1; off < NBUCKET; off <<= 1) {
        int t = (tid >= off) ? sh[tid - off] : 0;
        __syncthreads();
        sh[tid] += t;
        __syncthreads();
    }
    bucketBase[tid] = sh[tid] - v;
    if (tid == NBUCKET - 1) bucketBase[NBUCKET] = sh[NBUCKET - 1];
}

// ---- 3. scatter edges into bucket-grouped order (uint4 reads) ----
__global__ __launch_bounds__(256) void k_bucket_scatter(const uint4* __restrict__ src4,
                                                        const uint4* __restrict__ dst4,
                                                        const int* __restrict__ bucketBase,
                                                        const unsigned short* __restrict__ perBlockCnt,
                                                        unsigned* __restrict__ bucketData) {
    __shared__ unsigned slotBase[NBUCKET];
    slotBase[threadIdx.x] = (unsigned)bucketBase[threadIdx.x] +
                            (unsigned)perBlockCnt[threadIdx.x * NBLK + blockIdx.x];
    slotBase[threadIdx.x + 256] = (unsigned)bucketBase[threadIdx.x + 256] +
                                  (unsigned)perBlockCnt[(threadIdx.x + 256) * NBLK + blockIdx.x];
    __syncthreads();
    int base4 = blockIdx.x * (EPB / 4);
#pragma unroll
    for (int k = 0; k < EPB / 1024; k++) {
        int e4 = base4 + k * 256 + threadIdx.x;
        if (e4 < N_EDGES / 4) {
            uint4 s = src4[e4];
            uint4 d = dst4[e4];
            unsigned ss[4] = {s.x, s.y, s.z, s.w};
            unsigned dd[4] = {d.x, d.y, d.z, d.w};
#pragma unroll
            for (int j = 0; j < 4; j++) {
                unsigned b = dd[j] / NPB;
                unsigned ld = dd[j] - b * NPB;
                unsigned slot = atomicAdd(&slotBase[b], 1u);
                bucketData[slot] = ss[j] | (ld << 17);
            }
        }
    }
}

// ---- 4a. entry count per node + referenced bitmap ----
__global__ __launch_bounds__(256) void kx_cnt(const int* __restrict__ x,
                                              int* __restrict__ nodeEntCnt,
                                              unsigned* __restrict__ refBits) {
    int ent = blockIdx.x * blockDim.x + threadIdx.x;
    if (ent < N_ENTRIES) {
        int node = x[ent];
        atomicAdd(&nodeEntCnt[node], 1);
        atomicOr(&refBits[node >> 5], 1u << (node & 31));
    }
}

// ---- 4b. per-block exclusive scan of nodeEntCnt ----
__global__ __launch_bounds__(512) void kx_scan_local(const int* __restrict__ nodeEntCnt,
                                                     int* __restrict__ localE,
                                                     int* __restrict__ blockSumsE) {
    __shared__ int sh[SCAN_B];
    int g = blockIdx.x * SCAN_B + threadIdx.x;
    int v = (g < N_PAD) ? nodeEntCnt[g] : 0;
    sh[threadIdx.x] = v;
    __syncthreads();
    for (int off = 1; off < SCAN_B; off <<= 1) {
        int t = (threadIdx.x >= off) ? sh[threadIdx.x - off] : 0;
        __syncthreads();
        sh[threadIdx.x] += t;
        __syncthreads();
    }
    int incl = sh[threadIdx.x];
    if (g < N_PAD) localE[g] = incl - v;
    if (threadIdx.x == SCAN_B - 1) blockSumsE[blockIdx.x] = incl;
}

// ---- 4c. serial scan of 196 block sums ----
__global__ void kx_scan_blocks(const int* __restrict__ blockSumsE,
                               int* __restrict__ blockBaseE) {
    if (threadIdx.x == 0 && blockIdx.x == 0) {
        int s = 0;
        for (int i = 0; i < NSB; i++) {
            blockBaseE[i] = s;
            s += blockSumsE[i];
        }
    }
}

// ---- 4d. scatter entry ids grouped by node (localE becomes local END) ----
__global__ __launch_bounds__(256) void kx_scatter(const int* __restrict__ x,
                                                  int* __restrict__ localE,
                                                  const int* __restrict__ blockBaseE,
                                                  int* __restrict__ entGrouped) {
    int ent = blockIdx.x * blockDim.x + threadIdx.x;
    if (ent < N_ENTRIES) {
        int node = x[ent];
        int posL = atomicAdd(&localE[node], 1);
        entGrouped[blockBaseE[node >> 9] + posL] = ent;
    }
}

// ---- 5. per-bucket CSR build: full degrees; permute + write back ONLY
//         edges whose dst is referenced (≈56%) ----
__global__ __launch_bounds__(256) void k_bucket_csr(unsigned* __restrict__ bucketData,
                                                    const int* __restrict__ bucketBase,
                                                    const unsigned* __restrict__ refBits,
                                                    int* __restrict__ rowStart,
                                                    unsigned short* __restrict__ deg) {
    __shared__ unsigned words[BUCKET_CAP];
    __shared__ unsigned srcsorted[BUCKET_CAP];
    __shared__ unsigned nodeCount[NPB];
    __shared__ unsigned sscan[256];
    __shared__ unsigned cursor[NPB];
    __shared__ unsigned char refF[NPB];

    int b = blockIdx.x;
    int base = bucketBase[b];
    int cnt = bucketBase[b + 1] - base;
    if (cnt > BUCKET_CAP) cnt = BUCKET_CAP;
    int tid = threadIdx.x;

    for (int j = tid; j < NPB; j += 256) nodeCount[j] = 0;
    __syncthreads();

    for (int i = tid; i < cnt; i += 256) {
        unsigned w = bucketData[base + i];
        words[i] = w;
        atomicAdd(&nodeCount[w >> 17], 1u);
    }
    __syncthreads();

    int firstNode = b * NPB;
    unsigned refCnt = 0;
    if (tid < NPB) {
        int node = firstNode + tid;
        unsigned isRef = (refBits[node >> 5] >> (node & 31)) & 1u;
        refF[tid] = (unsigned char)isRef;
        refCnt = isRef ? nodeCount[tid] : 0;
        deg[node] = (unsigned short)nodeCount[tid];
    }
    sscan[tid] = refCnt;
    __syncthreads();
    for (int off = 1; off < 256; off <<= 1) {
        unsigned t = (tid >= off) ? sscan[tid - off] : 0;
        __syncthreads();
        sscan[tid] += t;
        __syncthreads();
    }

    if (tid < NPB) {
        unsigned excl = sscan[tid] - refCnt;
        rowStart[firstNode + tid] = base + (int)excl;
        cursor[tid] = excl;
    }
    __syncthreads();

    for (int i = tid; i < cnt; i += 256) {
        unsigned w = words[i];
        unsigned ld = w >> 17;
        if (refF[ld]) {
            unsigned slot = atomicAdd(&cursor[ld], 1u);
            srcsorted[slot] = w & 0x1FFFFu;
        }
    }
    __syncthreads();

    int refTotal = (int)sscan[255];
    for (int i = tid; i < refTotal; i += 256)
        bucketData[base + i] = srcsorted[i];
}

// ---- 6. W (f32, K x N) -> bf16 W^T (N x K) ----
__global__ void k_wtconv(const float* __restrict__ W, unsigned short* __restrict__ WTbf) {
    int i = blockIdx.x * blockDim.x + threadIdx.x;
    if (i >= D_OUT * F_IN) return;
    int n = i >> 8, k = i & 255;
    WTbf[i] = f2bf_bits(W[k * D_OUT + n]);
}

// ---- 7. MFMA GEMM: y[row] = dis[row] * (X[row] @ W), bf16 out ----
__global__ __launch_bounds__(256) void k_gemm_mfma(const float* __restrict__ feat,
                                                   const unsigned short* __restrict__ WTbf,
                                                   const unsigned short* __restrict__ deg,
                                                   unsigned short* __restrict__ y) {
    __shared__ unsigned short wt[64 * 264];
    int tid = threadIdx.x;
    {
        int r = tid >> 2, seg = tid & 3;
        const uint4* gsrc = (const uint4*)(WTbf + r * 256 + seg * 64);
        uint4* ldst = (uint4*)&wt[r * 264 + seg * 64];
#pragma unroll
        for (int q = 0; q < 8; q++) ldst[q] = gsrc[q];
    }
    __syncthreads();

    int wave = tid >> 6, lane = tid & 63;
    int quad = lane >> 4, m = lane & 15;
    int rowT = blockIdx.x * 64 + wave * 16;
    int row = rowT + m;
    int rowC = (row < N_NODES) ? row : (N_NODES - 1);
    const float* fb = feat + (size_t)rowC * F_IN + quad * 8;

    f32x4 acc0 = {0.f, 0.f, 0.f, 0.f};
    f32x4 acc1 = acc0, acc2 = acc0, acc3 = acc0;

#pragma unroll
    for (int kk = 0; kk < 8; kk++) {
        float4 x0 = *(const float4*)(fb + kk * 32);
        float4 x1 = *(const float4*)(fb + kk * 32 + 4);
        bf16x8 a;
        a[0] = (short)f2bf_bits(x0.x); a[1] = (short)f2bf_bits(x0.y);
        a[2] = (short)f2bf_bits(x0.z); a[3] = (short)f2bf_bits(x0.w);
        a[4] = (short)f2bf_bits(x1.x); a[5] = (short)f2bf_bits(x1.y);
        a[6] = (short)f2bf_bits(x1.z); a[7] = (short)f2bf_bits(x1.w);
        int kbase = kk * 32 + quad * 8;
        bf16x8 b0 = *(const bf16x8*)&wt[(0 * 16 + m) * 264 + kbase];
        bf16x8 b1 = *(const bf16x8*)&wt[(1 * 16 + m) * 264 + kbase];
        bf16x8 b2 = *(const bf16x8*)&wt[(2 * 16 + m) * 264 + kbase];
        bf16x8 b3 = *(const bf16x8*)&wt[(3 * 16 + m) * 264 + kbase];
        acc0 = __builtin_amdgcn_mfma_f32_16x16x32_bf16(a, b0, acc0, 0, 0, 0);
        acc1 = __builtin_amdgcn_mfma_f32_16x16x32_bf16(a, b1, acc1, 0, 0, 0);
        acc2 = __builtin_amdgcn_mfma_f32_16x16x32_bf16(a, b2, acc2, 0, 0, 0);
        acc3 = __builtin_amdgcn_mfma_f32_16x16x32_bf16(a, b3, acc3, 0, 0, 0);
    }

    float dv[4];
#pragma unroll
    for (int r = 0; r < 4; r++) {
        int rr = rowT + quad * 4 + r;
        dv[r] = rsqrtf((float)(deg[rr] + 1));
    }
#pragma unroll
    for (int r = 0; r < 4; r++) {
        int rr = rowT + quad * 4 + r;
        if (rr < N_NODES) {
            size_t o = (size_t)rr * D_OUT + m;
            y[o]      = f2bf_bits(acc0[r] * dv[r]);
            y[o + 16] = f2bf_bits(acc1[r] * dv[r]);
            y[o + 32] = f2bf_bits(acc2[r] * dv[r]);
            y[o + 48] = f2bf_bits(acc3[r] * dv[r]);
        }
    }
}

// ---- 8. dedup aggregation: one wave per node; unroll-8 gather MLP ----
__global__ __launch_bounds__(256) void k_agg(const int* __restrict__ entGrouped,
                                             const int* __restrict__ localE,
                                             const int* __restrict__ blockBaseE,
                                             const int* __restrict__ rowStart,
                                             const unsigned short* __restrict__ deg,
                                             const unsigned* __restrict__ sortedSrc,
                                             const unsigned short* __restrict__ y,
                                             const float* __restrict__ b,
                                             float* __restrict__ out) {
    int g = blockIdx.x * blockDim.x + threadIdx.x;
    int i = g >> 6, lane = g & 63;
    if (i >= N_PAD) return;
    int gEnd = blockBaseE[i >> 9] + localE[i];
    int gStart = (i == 0) ? 0 : (blockBaseE[(i - 1) >> 9] + localE[i - 1]);
    int cntEnt = gEnd - gStart;
    if (cntEnt <= 0) return;

    int start = rowStart[i];
    int cnt = deg[i];
    float disI = rsqrtf((float)(cnt + 1));
    float self = bfbits2f(y[(size_t)i * D_OUT + lane]);
    float s0 = 0.f, s1 = 0.f, s2 = 0.f, s3 = 0.f;
    float s4 = 0.f, s5 = 0.f, s6 = 0.f, s7 = 0.f;
    int e = 0;
    for (; e + 8 <= cnt; e += 8) {
        unsigned i0 = sortedSrc[start + e];
        unsigned i1 = sortedSrc[start + e + 1];
        unsigned i2 = sortedSrc[start + e + 2];
        unsigned i3 = sortedSrc[start + e + 3];
        unsigned i4 = sortedSrc[start + e + 4];
        unsigned i5 = sortedSrc[start + e + 5];
        unsigned i6 = sortedSrc[start + e + 6];
        unsigned i7 = sortedSrc[start + e + 7];
        s0 += bfbits2f(y[(size_t)i0 * D_OUT + lane]);
        s1 += bfbits2f(y[(size_t)i1 * D_OUT + lane]);
        s2 += bfbits2f(y[(size_t)i2 * D_OUT + lane]);
        s3 += bfbits2f(y[(size_t)i3 * D_OUT + lane]);
        s4 += bfbits2f(y[(size_t)i4 * D_OUT + lane]);
        s5 += bfbits2f(y[(size_t)i5 * D_OUT + lane]);
        s6 += bfbits2f(y[(size_t)i6 * D_OUT + lane]);
        s7 += bfbits2f(y[(size_t)i7 * D_OUT + lane]);
    }
    for (; e + 2 <= cnt; e += 2) {
        unsigned i0 = sortedSrc[start + e];
        unsigned i1 = sortedSrc[start + e + 1];
        s0 += bfbits2f(y[(size_t)i0 * D_OUT + lane]);
        s1 += bfbits2f(y[(size_t)i1 * D_OUT + lane]);
    }
    if (e < cnt) {
        unsigned i0 = sortedSrc[start + e];
        s0 += bfbits2f(y[(size_t)i0 * D_OUT + lane]);
    }
    float sum = self + (((s0 + s1) + (s2 + s3)) + ((s4 + s5) + (s6 + s7)));
    float val = disI * sum + b[lane];
    for (int j = 0; j < cntEnt; j++) {
        int ent = entGrouped[gStart + j];
        out[(size_t)ent * D_OUT + lane] = val;
    }
}

extern "C" void kernel_launch(void* const* d_in, const int* in_sizes, int n_in,
                              void* d_out, int out_size, void* d_ws, size_t ws_size,
                              hipStream_t stream) {
    const float* feat     = (const float*)d_in[0];
    const int* edge_index = (const int*)d_in[1];
    const float* W        = (const float*)d_in[2];
    const float* bsrc     = (const float*)d_in[3];
    const int* x          = (const int*)d_in[4];
    float* out            = (float*)d_out;

    const uint4* src4 = (const uint4*)edge_index;
    const uint4* dst4 = (const uint4*)(edge_index + N_EDGES);

    // workspace layout (256B aligned) — ~25.9 MB total (< proven 27.3 MB).
    // perBlockCnt region is reused: perBlockCnt (dead after k_bucket_scatter)
    // -> nodeEntCnt (dead after kx_scan_local) -> entGrouped (alive in k_agg).
    char* ws = (char*)d_ws;
    size_t off = 0;
    auto alloc = [&](size_t bytes) {
        size_t o = off;
        off = (off + bytes + 255) & ~(size_t)255;
        return o;
    };
    int* bucketBase = (int*)(ws + alloc((size_t)(NBUCKET + 1) * 4));
    int* bucketTot  = (int*)(ws + alloc((size_t)NBUCKET * 4));
    size_t pcOff = alloc((size_t)N_PAD * 4);   // 401,408 B >= 512*391*2
    unsigned short* perBlockCnt = (unsigned short*)(ws + pcOff);
    int* nodeEntCnt = (int*)(ws + pcOff);
    int* entGrouped = (int*)(ws + pcOff);
    unsigned* refBits = (unsigned*)(ws + alloc((size_t)(N_PAD / 8)));
    int* rowStart   = (int*)(ws + alloc((size_t)N_PAD * 4));
    unsigned short* deg = (unsigned short*)(ws + alloc((size_t)N_PAD * 2));
    unsigned short* WTbf = (unsigned short*)(ws + alloc((size_t)D_OUT * F_IN * 2));
    int* localE     = (int*)(ws + alloc((size_t)N_PAD * 4));
    int* blockSumsE = (int*)(ws + alloc((size_t)NSB * 4));
    int* blockBaseE = (int*)(ws + alloc((size_t)NSB * 4));
    unsigned* bucketData = (unsigned*)(ws + alloc((size_t)N_EDGES * 4));
    unsigned short* y = (unsigned short*)(ws + alloc((size_t)N_NODES * D_OUT * 2));
    (void)ws_size; (void)in_sizes; (void)n_in; (void)out_size;

    const int T = 256;
    k_hist<<<NBLK, T, 0, stream>>>(dst4, perBlockCnt);
    k_colscan_w<<<(NBUCKET * 64 + T - 1) / T, T, 0, stream>>>(perBlockCnt, bucketTot);
    k_basescan<<<1, NBUCKET, 0, stream>>>(bucketTot, bucketBase);
    k_bucket_scatter<<<NBLK, T, 0, stream>>>(src4, dst4, bucketBase, perBlockCnt, bucketData);
    // perBlockCnt dead; region becomes nodeEntCnt
    hipMemsetAsync(nodeEntCnt, 0, (size_t)N_PAD * 4, stream);
    hipMemsetAsync(refBits, 0, (size_t)(N_PAD / 8), stream);
    kx_cnt<<<(N_ENTRIES + T - 1) / T, T, 0, stream>>>(x, nodeEntCnt, refBits);
    kx_scan_local<<<NSB, SCAN_B, 0, stream>>>(nodeEntCnt, localE, blockSumsE);
    kx_scan_blocks<<<1, 64, 0, stream>>>(blockSumsE, blockBaseE);
    kx_scatter<<<(N_ENTRIES + T - 1) / T, T, 0, stream>>>(x, localE, blockBaseE, entGrouped);
    k_bucket_csr<<<NBUCKET, T, 0, stream>>>(bucketData, bucketBase, refBits, rowStart, deg);
    k_wtconv<<<(D_OUT * F_IN + T - 1) / T, T, 0, stream>>>(W, WTbf);
    k_gemm_mfma<<<(N_NODES + 63) / 64, T, 0, stream>>>(feat, WTbf, deg, y);
    k_agg<<<((size_t)N_PAD * 64 + T - 1) / T, T, 0, stream>>>(
        entGrouped, localE, blockBaseE, rowStart, deg, bucketData, y, bsrc, out);
}